// Round 6
// baseline (1262.358 us; speedup 1.0000x reference)
//
#include <hip/hip_runtime.h>

#define CIN 32
#define COUT 64
#define OD0 100
#define OD1 100
#define OD2 8
#define NUMOUT (2 * OD0 * OD1 * OD2)   // 160000
#define NTILE (NUMOUT / 16)            // 10000
#define NB2 (27 * NUMOUT)              // 4,320,000 buckets: key = off*NUMOUT + cell
#define CH2 5120                       // scan chunk (256 thr x 20)
#define SCB ((NB2 + CH2 - 1) / CH2)    // 844 scan blocks
#define NB2PAD (SCB * CH2)             // 4,321,280 (tail zeros -> sentinel automatic)
#define NWPK (27 * 64 * 32)            // 55296 bf16 prepacked W
#define GRID 1024
#define GSZ (GRID * 256)

typedef short short8 __attribute__((ext_vector_type(8)));
typedef float f32x4 __attribute__((ext_vector_type(4)));

__device__ __forceinline__ unsigned short f2bf(float f) {
    unsigned u = __float_as_uint(f);
    u += 0x7FFFu + ((u >> 16) & 1u);      // RNE
    return (unsigned short)(u >> 16);
}

// ---------- tap enumeration (stride-2, pad-1: <=2 taps per dim) ----------

template <typename F>
__device__ __forceinline__ void for_taps(int4 c, F f) {
    int bb = c.x, pz = c.y, py = c.z, px = c.w;
    int oz[2], ozo[2], nz = 0, oy[2], oyo[2], ny = 0, ox[2], oxo[2], nx = 0;
#pragma unroll
    for (int o = 0; o < 3; o++) {
        int num = pz + 1 - o;
        if (num >= 0 && !(num & 1) && (num >> 1) < OD0) { oz[nz] = num >> 1; ozo[nz] = o; nz++; }
        num = py + 1 - o;
        if (num >= 0 && !(num & 1) && (num >> 1) < OD1) { oy[ny] = num >> 1; oyo[ny] = o; ny++; }
        num = px + 1 - o;
        if (num >= 0 && !(num & 1) && (num >> 1) < OD2) { ox[nx] = num >> 1; oxo[nx] = o; nx++; }
    }
    for (int a = 0; a < nz; a++)
        for (int b = 0; b < ny; b++)
            for (int d = 0; d < nx; d++) {
                int cell = ((bb * OD0 + oz[a]) * OD1 + oy[b]) * OD2 + ox[d];
                int off = (ozo[a] * 3 + oyo[b]) * 3 + oxo[d];
                f(cell, off);
            }
}

// ---------- parallel two-level radix select (one full 256-thread block) ----------

__device__ void selectDev(const int* __restrict__ hist, int rank, int* __restrict__ out) {
    __shared__ int p1[256];
    __shared__ int sc[256];
    __shared__ int wT, wB;
    int t = threadIdx.x;
    const int* h = hist + t * 256;
    int mySum = 0;
    for (int j = 0; j < 256; j++) mySum += h[j];
    sc[t] = mySum;
    p1[t] = mySum;
    __syncthreads();
    for (int d = 1; d < 256; d <<= 1) {
        int a = (t >= d) ? sc[t - d] : 0;
        __syncthreads();
        sc[t] += a;
        __syncthreads();
    }
    {
        int excl = sc[t] - p1[t];
        if (rank >= excl && rank < sc[t]) { wT = t; wB = excl; }
    }
    __syncthreads();
    int hiT = wT, r2 = rank - wB;
    int hv = hist[hiT * 256 + t];
    sc[t] = hv;
    __syncthreads();
    for (int d = 1; d < 256; d <<= 1) {
        int a = (t >= d) ? sc[t - d] : 0;
        __syncthreads();
        sc[t] += a;
        __syncthreads();
    }
    {
        int excl = sc[t] - hv;
        if (r2 >= excl && r2 < sc[t]) { out[0] = hiT * 256 + t; out[1] = r2 - excl; }
    }
    __syncthreads();
}

// ---------- grid barrier: per-instance counter slot (zeroed by host memset) ----------

__device__ __forceinline__ void gridBarrier(unsigned* bar, int k) {
    __syncthreads();
    if (threadIdx.x == 0) {
        __threadfence();
        atomicAdd(&bar[k], 1u);
        while (atomicAdd(&bar[k], 0u) < (unsigned)GRID)
            __builtin_amdgcn_s_sleep(8);
    }
    __syncthreads();
}

// ---------- the fused persistent kernel ----------

__global__ void __launch_bounds__(256, 4)
mega_kernel(const float* __restrict__ feat, const int* __restrict__ coors,
            const float* __restrict__ mask, const float* __restrict__ W,
            float* __restrict__ out, int n, int rank,
            unsigned* bar, int* histHi, int* histLo, int* sel, unsigned* mm,
            unsigned short* wpk, unsigned* blockSums, unsigned* blockBase,
            unsigned* cnt2, unsigned* base2, unsigned* cursor2,
            unsigned* pairs, unsigned pcap) {
    const int t = threadIdx.x;
    const int gid = blockIdx.x * 256 + t;

    // ---- P0: zero working arrays + prepack W (bf16 B-fragment order) ----
    for (int i = gid; i < 65536; i += GSZ) histHi[i] = 0;
    for (int i = gid; i < 65536; i += GSZ) histLo[i] = 0;
    for (int i = gid; i < NUMOUT; i += GSZ) mm[i] = 0u;
    for (int i = gid; i < 1024; i += GSZ) blockSums[i] = 0u;
    {
        uint4 z4 = make_uint4(0u, 0u, 0u, 0u);
        for (int i = gid; i < NB2PAD / 4; i += GSZ) ((uint4*)cnt2)[i] = z4;
    }
    for (int i = gid; i < NWPK; i += GSZ) {
        int j = i & 7, b = (i >> 3) & 3, lane = (i >> 5) & 63, off = i >> 11;
        int k = ((lane >> 4) << 3) + j;
        int cout = (b << 4) + (lane & 15);
        wpk[i] = f2bf(W[off * (CIN * COUT) + k * COUT + cout]);
    }
    gridBarrier(bar, 0);

    // ---- P1: hi-16 mask histogram + bucket counts + per-cell max-mask ----
    for (int i = gid; i < n; i += GSZ) {
        unsigned mbits = __float_as_uint(mask[i]);
        atomicAdd(&histHi[mbits >> 16], 1);
        int4 c = ((const int4*)coors)[i];
        for_taps(c, [&](int cell, int off) {
            atomicAdd(&cnt2[off * NUMOUT + cell], 1u);
            atomicMax(&mm[cell], mbits);
        });
    }
    gridBarrier(bar, 1);

    // ---- P2a: per-chunk exclusive scan of cnt2 (20 elems/thread) ----
    if ((int)blockIdx.x < SCB) {
        __shared__ unsigned ssum[256];
        int base = blockIdx.x * CH2 + t * 20;
        unsigned tot = 0;
#pragma unroll
        for (int q = 0; q < 5; q++) {
            uint4 v = *(const uint4*)(cnt2 + base + q * 4);
            tot += v.x + v.y + v.z + v.w;
        }
        ssum[t] = tot;
        __syncthreads();
        for (int d = 1; d < 256; d <<= 1) {
            unsigned a = (t >= d) ? ssum[t - d] : 0u;
            __syncthreads();
            ssum[t] += a;
            __syncthreads();
        }
        if (t == 255) blockSums[blockIdx.x] = ssum[255];
        unsigned run = ssum[t] - tot;
#pragma unroll
        for (int q = 0; q < 5; q++) {
            uint4 v = *(const uint4*)(cnt2 + base + q * 4);
            base2[base + q * 4 + 0] = run; run += v.x;
            base2[base + q * 4 + 1] = run; run += v.y;
            base2[base + q * 4 + 2] = run; run += v.z;
            base2[base + q * 4 + 3] = run; run += v.w;
        }
    }
    gridBarrier(bar, 2);

    // ---- P2b: block0 scans chunk sums; block1 does level-1 select ----
    if (blockIdx.x == 0) {
        __shared__ unsigned s2[256];
        unsigned v0 = blockSums[t * 4 + 0], v1 = blockSums[t * 4 + 1];
        unsigned v2 = blockSums[t * 4 + 2], v3 = blockSums[t * 4 + 3];
        unsigned tot = v0 + v1 + v2 + v3;
        s2[t] = tot;
        __syncthreads();
        for (int d = 1; d < 256; d <<= 1) {
            unsigned a = (t >= d) ? s2[t - d] : 0u;
            __syncthreads();
            s2[t] += a;
            __syncthreads();
        }
        unsigned run = s2[t] - tot;
        blockBase[t * 4 + 0] = run; run += v0;
        blockBase[t * 4 + 1] = run; run += v1;
        blockBase[t * 4 + 2] = run; run += v2;
        blockBase[t * 4 + 3] = run; run += v3;
    }
    if (blockIdx.x == 1) selectDev(histHi, rank, sel);
    gridBarrier(bar, 3);

    // ---- P3: add-back + cursor copy + lo-16 histogram ----
    for (int i = gid; i < NB2PAD; i += GSZ) {
        unsigned v = base2[i] + blockBase[(unsigned)i / CH2];
        base2[i] = v;
        cursor2[i] = v;
    }
    {
        int s0 = sel[0];
        for (int i = gid; i < n; i += GSZ) {
            unsigned bits = __float_as_uint(mask[i]);
            if ((int)(bits >> 16) == s0) atomicAdd(&histLo[bits & 0xFFFFu], 1);
        }
    }
    gridBarrier(bar, 4);

    // ---- P4: fill pair list (point index only); block0 also does level-2 select ----
    if (blockIdx.x == 0) selectDev(histLo, sel[1], sel + 2);
    for (int i = gid; i < n; i += GSZ) {
        int4 c = ((const int4*)coors)[i];
        for_taps(c, [&](int cell, int off) {
            unsigned pos = atomicAdd(&cursor2[off * NUMOUT + cell], 1u);
            if (pos < pcap) pairs[pos] = (unsigned)i;
        });
    }
    gridBarrier(bar, 5);

    // ---- P5: gather. block = tile (grid-stride); 4 waves split the 27 offsets.
    // A-row index == cell -> C rows map 1:1 to cells: accumulate whole tile in
    // 16 VGPRs per wave; single LDS-atomic scatter per tile per wave.
    {
        __shared__ float accL[16 * 64];
        int wv = t >> 6, lane = t & 63, l16 = lane & 15, quad = lane >> 4;
        unsigned thrBits = (((unsigned)sel[0]) << 16) | (unsigned)sel[2];

        for (int tile = blockIdx.x; tile < NTILE; tile += GRID) {
            ((float4*)accL)[t] = make_float4(0.f, 0.f, 0.f, 0.f);
            __syncthreads();

            f32x4 a0 = {0.f, 0.f, 0.f, 0.f}, a1 = a0, a2 = a0, a3 = a0;

            for (int off = wv; off < 27; off += 4) {
                unsigned v = 0;
                if (lane <= 16) v = base2[off * NUMOUT + tile * 16 + lane];
                unsigned s = __shfl(v, l16);
                unsigned e = __shfl(v, l16 + 1);
                unsigned m = e - s;
                if (__ballot(m != 0) == 0) continue;

                const unsigned short* wb = wpk + (size_t)(off * 64 + lane) * 32;
                short8 B0 = *(const short8*)(wb + 0);
                short8 B1 = *(const short8*)(wb + 8);
                short8 B2 = *(const short8*)(wb + 16);
                short8 B3 = *(const short8*)(wb + 24);

                for (unsigned r = 0;; r++) {
                    unsigned long long act = __ballot(r < m);
                    if (!(act & 0xFFFFull)) break;
                    short8 A = {0, 0, 0, 0, 0, 0, 0, 0};
                    unsigned idx = s + r;
                    if (r < m && idx < pcap) {
                        unsigned p = pairs[idx];
                        const float4* fp = (const float4*)(feat + ((size_t)p << 5) + (quad << 3));
                        float4 fa = fp[0], fb = fp[1];
                        A[0] = (short)f2bf(fa.x); A[1] = (short)f2bf(fa.y);
                        A[2] = (short)f2bf(fa.z); A[3] = (short)f2bf(fa.w);
                        A[4] = (short)f2bf(fb.x); A[5] = (short)f2bf(fb.y);
                        A[6] = (short)f2bf(fb.z); A[7] = (short)f2bf(fb.w);
                    }
                    a0 = __builtin_amdgcn_mfma_f32_16x16x32_bf16(A, B0, a0, 0, 0, 0);
                    a1 = __builtin_amdgcn_mfma_f32_16x16x32_bf16(A, B1, a1, 0, 0, 0);
                    a2 = __builtin_amdgcn_mfma_f32_16x16x32_bf16(A, B2, a2, 0, 0, 0);
                    a3 = __builtin_amdgcn_mfma_f32_16x16x32_bf16(A, B3, a3, 0, 0, 0);
                }
            }

            // scatter: C row (quad*4+r) == cell, col l16 within cout-block
#pragma unroll
            for (int r = 0; r < 4; r++) {
                int row = quad * 4 + r;
                atomicAdd(&accL[row * 64 + 0 + l16], a0[r]);
                atomicAdd(&accL[row * 64 + 16 + l16], a1[r]);
                atomicAdd(&accL[row * 64 + 32 + l16], a2[r]);
                atomicAdd(&accL[row * 64 + 48 + l16], a3[r]);
            }
            __syncthreads();

            int cell = t >> 4;                 // (t*4)/64
            float4 o4 = ((float4*)accL)[t];
            if (mm[tile * 16 + cell] < thrBits) o4 = make_float4(0.f, 0.f, 0.f, 0.f);
            ((float4*)(out + ((size_t)tile << 10)))[t] = o4;
            __syncthreads();
        }
    }
}

// ---------- host ----------

extern "C" void kernel_launch(void* const* d_in, const int* in_sizes, int n_in,
                              void* d_out, int out_size, void* d_ws, size_t ws_size,
                              hipStream_t stream) {
    const float* feat  = (const float*)d_in[0];   // (N, 32) f32
    const int*   coors = (const int*)d_in[1];     // (N, 4)  i32
    const float* mask  = (const float*)d_in[2];   // (N,)    f32
    const float* W     = (const float*)d_in[3];   // (3,3,3,32,64) f32

    int n = in_sizes[2];
    int rank = (int)(n * 0.5);

    char* ws = (char*)d_ws;
    size_t o = 0;
    unsigned* bar = (unsigned*)(ws + o);        o += 256;                 // memset 256 B
    int* histHi = (int*)(ws + o);               o += 65536 * 4;
    int* histLo = (int*)(ws + o);               o += 65536 * 4;
    int* sel    = (int*)(ws + o);               o += 256;
    unsigned* mm = (unsigned*)(ws + o);         o += (size_t)NUMOUT * 4;
    unsigned short* wpk = (unsigned short*)(ws + o); o += (size_t)NWPK * 2;
    unsigned* blockSums = (unsigned*)(ws + o);  o += 1024 * 4;
    unsigned* blockBase = (unsigned*)(ws + o);  o += 1024 * 4;
    unsigned* cnt2 = (unsigned*)(ws + o);       o += (size_t)NB2PAD * 4;
    unsigned* base2 = (unsigned*)(ws + o);      o += (size_t)NB2PAD * 4;
    unsigned* cursor2 = (unsigned*)(ws + o);    o += (size_t)NB2PAD * 4;
    o = (o + 255) & ~(size_t)255;
    unsigned* pairs = (unsigned*)(ws + o);

    size_t avail = (ws_size > o) ? (ws_size - o) : 0;
    size_t maxPairs = (size_t)n * 8;
    size_t pcap = avail / 4;
    if (pcap > maxPairs) pcap = maxPairs;

    hipMemsetAsync(bar, 0, 256, stream);
    mega_kernel<<<GRID, 256, 0, stream>>>(feat, coors, mask, W, (float*)d_out,
                                          n, rank, bar, histHi, histLo, sel, mm,
                                          wpk, blockSums, blockBase,
                                          cnt2, base2, cursor2, pairs,
                                          (unsigned)pcap);
}